// Round 17
// baseline (121.415 us; speedup 1.0000x reference)
//
#include <hip/hip_runtime.h>

#define TT 4
#define BB 32
#define CC 256
#define NN 256
#define EPSf 1e-5f
#define MULTf 0.35355339059327373f
#define MARGINQ 1e-2f
#define FCAP 2048u

typedef __attribute__((ext_vector_type(8))) short s16x8;
typedef __attribute__((ext_vector_type(4))) float f32x4;
typedef unsigned char uchar;
typedef unsigned int uint;
typedef unsigned short ushort;

__device__ __forceinline__ ushort f2bf_rn(float f) {
  uint u = __float_as_uint(f);
  u = (u + 0x7FFFu + ((u >> 16) & 1u)) >> 16;
  return (ushort)u;
}
__device__ __forceinline__ float bf2f(ushort b) {
  return __uint_as_float(((uint)b) << 16);
}

// ---------------------------------------------------------------------------
// K1 (front): blocks 0..255 = lif(x) -> xsF fragments + xsP packed bits;
// blocks 256..383 = weight prep (qkv single-split scaled; proj 2-split).
// [validated R10/R11/R15/R16; flag zeroing removed]
// ---------------------------------------------------------------------------
__global__ __launch_bounds__(256) void k_front(
    const float* __restrict__ x, uchar* __restrict__ xsF, uchar* __restrict__ xsP,
    const float* __restrict__ qw, const float* __restrict__ kw,
    const float* __restrict__ vw, const float* __restrict__ pw,
    const float* __restrict__ qga, const float* __restrict__ qva,
    const float* __restrict__ kga, const float* __restrict__ kva,
    const float* __restrict__ vga, const float* __restrict__ vva,
    uchar* __restrict__ wfq, uchar* __restrict__ wfp) {
  const int tid = threadIdx.x;
  const int bid = blockIdx.x;
  if (bid < 256) {
#pragma clang fp contract(off)
    const int b = bid >> 3;
    const int ksq = bid & 7;
    const int oct = tid >> 6;    // 0..3
    const int nq = tid & 63;     // n-quad
    const int c0 = ksq * 32 + oct * 8;
    const int n0 = nq * 4;
    const size_t stride = (size_t)BB * CC * NN;
    const float* xb = x + ((size_t)b * CC + c0) * NN + n0;

    float v[8][4];
#pragma unroll
    for (int j = 0; j < 8; ++j)
#pragma unroll
      for (int nn = 0; nn < 4; ++nn) v[j][nn] = 0.f;

#pragma unroll
    for (int t = 0; t < TT; ++t) {
      ushort sp[8][4];
      uint pm[4] = {0, 0, 0, 0};
#pragma unroll
      for (int j = 0; j < 8; ++j) {
        const float4 xv = *reinterpret_cast<const float4*>(xb + t * stride + (size_t)j * NN);
        const float xa[4] = {xv.x, xv.y, xv.z, xv.w};
#pragma unroll
        for (int nn = 0; nn < 4; ++nn) {
          float d = (xa[nn] - v[j][nn]) * 0.5f;
          v[j][nn] = v[j][nn] + d;
          bool s = (v[j][nn] >= 1.0f);
          sp[j][nn] = s ? (ushort)0x3F80 : (ushort)0;
          if (s) { v[j][nn] = 0.f; pm[nn] |= 1u << j; }
        }
      }
#pragma unroll
      for (int nn = 0; nn < 4; ++nn) {
        const int n = n0 + nn;
        uint4* dst = reinterpret_cast<uint4*>(xsF) +
                     (((size_t)(t * BB + b) * 16 + (n >> 4)) * 512 + ksq * 64 + oct * 16 + (n & 15));
        uint4 o;
        o.x = (uint)sp[0][nn] | ((uint)sp[1][nn] << 16);
        o.y = (uint)sp[2][nn] | ((uint)sp[3][nn] << 16);
        o.z = (uint)sp[4][nn] | ((uint)sp[5][nn] << 16);
        o.w = (uint)sp[6][nn] | ((uint)sp[7][nn] << 16);
        *dst = o;
        xsP[(((size_t)(t * BB + b) * NN + n) << 5) + ksq * 4 + oct] = (uchar)pm[nn];
      }
    }
  } else {
    const int gid = (bid - 256) * 256 + tid;  // 0..32767
    const int ob2 = gid >> 9;                 // 0..63
    const int e = gid & 511;
    const int ks = e >> 6, l = e & 63;
    const int c0 = ks * 32 + (l >> 4) * 8;
    if (ob2 < 48) {
      const int sel = ob2 >> 4;
      const float* Wb = sel == 0 ? qw : (sel == 1 ? kw : vw);
      const float* G = sel == 0 ? qga : (sel == 1 ? kga : vga);
      const float* Vr = sel == 0 ? qva : (sel == 1 ? kva : vva);
      const int ocr = (ob2 & 15) * 16 + (l & 15);
      const float inv = G[ocr] / sqrtf(Vr[ocr] + EPSf);
      const float* W = Wb + (size_t)ocr * CC;
      float wv[8];
      *reinterpret_cast<float4*>(&wv[0]) = *reinterpret_cast<const float4*>(W + c0);
      *reinterpret_cast<float4*>(&wv[4]) = *reinterpret_cast<const float4*>(W + c0 + 4);
      ushort hi[8];
#pragma unroll
      for (int j = 0; j < 8; ++j) hi[j] = f2bf_rn(wv[j] * inv);
      *reinterpret_cast<uint4*>(wfq + (((size_t)ob2 * 8 + ks) * 64 + l) * 16) =
          *reinterpret_cast<const uint4*>(hi);
    } else {
      const int ob = ob2 - 48;
      const float* W = pw + ((size_t)(ob * 16 + (l & 15))) * CC;
      float wv[8];
      *reinterpret_cast<float4*>(&wv[0]) = *reinterpret_cast<const float4*>(W + c0);
      *reinterpret_cast<float4*>(&wv[4]) = *reinterpret_cast<const float4*>(W + c0 + 4);
      ushort hi[8], lo[8];
#pragma unroll
      for (int j = 0; j < 8; ++j) {
        hi[j] = f2bf_rn(wv[j]);
        lo[j] = f2bf_rn(wv[j] - bf2f(hi[j]));
      }
      const size_t base = (((size_t)ob * 8 + ks) * 64 + l) * 16;
      const size_t sstr = (size_t)16 * 8 * 64 * 16;
      *reinterpret_cast<uint4*>(wfp + base) = *reinterpret_cast<const uint4*>(hi);
      *reinterpret_cast<uint4*>(wfp + sstr + base) = *reinterpret_cast<const uint4*>(lo);
    }
  }
}

// ---------------------------------------------------------------------------
// K4: fused q/k/v conv (MFMA, single-split scaled bf16) + folded-BN + LIF
// + IN-BLOCK exact fixer. Flags collected in an LDS list; after the qp
// stores drain at __syncthreads, each thread recomputes its flagged
// elements with the bitwise-exact ascending-c chain (validated k_fix body;
// this block exclusively owns the patched qp words) and patches atomically.
// ---------------------------------------------------------------------------
__global__ __launch_bounds__(256, 2) void k_qkv_mfma(
    const uchar* __restrict__ xsF, const uchar* __restrict__ wfq,
    const uchar* __restrict__ xsP,
    const float* __restrict__ qw, const float* __restrict__ kw, const float* __restrict__ vw,
    const float* __restrict__ qga, const float* __restrict__ qbe, const float* __restrict__ qme, const float* __restrict__ qva,
    const float* __restrict__ kga, const float* __restrict__ kbe, const float* __restrict__ kme, const float* __restrict__ kva,
    const float* __restrict__ vga, const float* __restrict__ vbe, const float* __restrict__ vme, const float* __restrict__ vva,
    ushort* __restrict__ qp) {
  __shared__ uint flct;
  __shared__ uint flst[FCAP];
  const int tid = threadIdx.x;
  const int wc = tid >> 6, lane = tid & 63;
  const int lhi = lane >> 4, llo = lane & 15;
  const int bid = blockIdx.x;
  const int xcd = bid & 7;
  const int r0 = bid >> 3;
  const int j = r0 % 12;                // oc-block 0..11
  const int g = (r0 / 12) * 8 + xcd;    // group 0..127
  const int b = g >> 2, ntile = g & 3;
  const int oc0 = j * 64;
  const int sel = j >> 2;
  const float* G  = sel == 0 ? qga : (sel == 1 ? kga : vga);
  const float* Be = sel == 0 ? qbe : (sel == 1 ? kbe : vbe);
  const float* Mn = sel == 0 ? qme : (sel == 1 ? kme : vme);
  const float* Vr = sel == 0 ? qva : (sel == 1 ? kva : vva);
  const float* Wsel = sel == 0 ? qw : (sel == 1 ? kw : vw);

  if (tid == 0) flct = 0;
  __syncthreads();

  s16x8 wfr[4][8];
#pragma unroll
  for (int mf = 0; mf < 4; ++mf)
#pragma unroll
    for (int ks = 0; ks < 8; ++ks)
      wfr[mf][ks] = *reinterpret_cast<const s16x8*>(
          wfq + (((size_t)(j * 4 + mf) * 8 + ks) * 64 + lane) * 16);

  float bias8[4][4];
#pragma unroll
  for (int mf = 0; mf < 4; ++mf)
#pragma unroll
    for (int rr = 0; rr < 4; ++rr) {
      const int ocb = (j & 3) * 64 + mf * 16 + lhi * 4 + rr;
      const float inv = G[ocb] / sqrtf(Vr[ocb] + EPSf);
      bias8[mf][rr] = Be[ocb] - Mn[ocb] * inv;
    }

  float vst[4][4];
#pragma unroll
  for (int mf = 0; mf < 4; ++mf)
#pragma unroll
    for (int rr = 0; rr < 4; ++rr) vst[mf][rr] = 0.f;
  uint fl = 0;
  ushort qm[TT][4];
  const int nb = ntile * 4 + wc;

#define BPTR(t_, ks_)                                                   \
  reinterpret_cast<const s16x8*>(                                       \
      xsF + ((((size_t)((t_) * BB + b) * 16 + nb) * 512 + (ks_) * 64 + lane) * 16))

  s16x8 bfr[8];
#pragma unroll
  for (int ks = 0; ks < 8; ++ks) bfr[ks] = *BPTR(0, ks);

#pragma unroll
  for (int t = 0; t < TT; ++t) {
    f32x4 acc[4];
#pragma unroll
    for (int mf = 0; mf < 4; ++mf) acc[mf] = (f32x4){0.f, 0.f, 0.f, 0.f};

#pragma unroll
    for (int ks = 0; ks < 8; ++ks) {
#pragma unroll
      for (int mf = 0; mf < 4; ++mf)
        acc[mf] = __builtin_amdgcn_mfma_f32_16x16x32_bf16(wfr[mf][ks], bfr[ks], acc[mf], 0, 0, 0);
      if (t < TT - 1) bfr[ks] = *BPTR(t + 1, ks);
    }

#pragma unroll
    for (int mf = 0; mf < 4; ++mf)
#pragma unroll
      for (int rr = 0; rr < 4; ++rr) {
        float y = acc[mf][rr] + bias8[mf][rr];
        float v = vst[mf][rr];
        v = v + (y - v) * 0.5f;
        const bool sp = (v >= 1.0f);
        if (fabsf(v - 1.0f) < MARGINQ) fl |= 1u << (mf * 4 + rr);
        const unsigned long long m = __ballot(sp);
        if (llo == rr) qm[t][mf] = (ushort)((m >> (lhi * 16)) & 0xFFFFull);
        vst[mf][rr] = sp ? 0.f : v;
      }
  }
#undef BPTR

  // write unfixed packed spikes
  if (llo < 4) {
#pragma unroll
    for (int t = 0; t < TT; ++t) {
      ushort* qrow = qp + (size_t)(t * BB + b) * 768 * 16;
#pragma unroll
      for (int mf = 0; mf < 4; ++mf) {
        const int oc = oc0 + mf * 16 + lhi * 4 + llo;
        qrow[(size_t)oc * 16 + ntile * 4 + wc] = qm[t][mf];
      }
    }
  }

  // emit flags to LDS list
  if (fl) {
#pragma unroll
    for (int mf = 0; mf < 4; ++mf)
#pragma unroll
      for (int rr = 0; rr < 4; ++rr)
        if (fl & (1u << (mf * 4 + rr))) {
          const int oc = oc0 + mf * 16 + lhi * 4 + rr;
          const int n = ntile * 64 + wc * 16 + llo;
          const uint idx = atomicAdd(&flct, 1u);
          if (idx < FCAP) flst[idx] = ((uint)oc << 8) | (uint)n;
        }
  }
  __syncthreads();  // drains qp stores (vmcnt 0 before barrier) + flag list

  // in-block exact fixer (validated k_fix body; this block owns these words)
  {
#pragma clang fp contract(off)
    uint* qp32 = (uint*)qp;
    const uint cnt = min(flct, FCAP);
    for (uint i = tid; i < cnt; i += 256) {
      const uint e = flst[i];
      const int n = (int)(e & 255);
      const int oc = (int)(e >> 8);
      const int ocl = oc & 255;
      const float* W = Wsel + (size_t)ocl * CC;

      uint bw[4][8];
#pragma unroll
      for (int t = 0; t < TT; ++t) {
        const uint4* p = reinterpret_cast<const uint4*>(
            xsP + (((size_t)(t * BB + b) * NN + n) << 5));
        uint4 a = p[0], c4 = p[1];
        bw[t][0] = a.x;  bw[t][1] = a.y;  bw[t][2] = a.z;  bw[t][3] = a.w;
        bw[t][4] = c4.x; bw[t][5] = c4.y; bw[t][6] = c4.z; bw[t][7] = c4.w;
      }

      const float4* W4 = reinterpret_cast<const float4*>(W);
      float a0 = 0.f, a1 = 0.f, a2 = 0.f, a3 = 0.f;
#pragma unroll
      for (int gg = 0; gg < 32; ++gg) {
        const float4 w0 = W4[2 * gg];
        const float4 w1 = W4[2 * gg + 1];
        const uint s0 = bw[0][gg >> 2] >> ((gg & 3) * 8);
        const uint s1 = bw[1][gg >> 2] >> ((gg & 3) * 8);
        const uint s2 = bw[2][gg >> 2] >> ((gg & 3) * 8);
        const uint s3 = bw[3][gg >> 2] >> ((gg & 3) * 8);
        const float wv[8] = {w0.x, w0.y, w0.z, w0.w, w1.x, w1.y, w1.z, w1.w};
#pragma unroll
        for (int jj = 0; jj < 8; ++jj) {
          a0 = fmaf(wv[jj], (float)((s0 >> jj) & 1u), a0);
          a1 = fmaf(wv[jj], (float)((s1 >> jj) & 1u), a1);
          a2 = fmaf(wv[jj], (float)((s2 >> jj) & 1u), a2);
          a3 = fmaf(wv[jj], (float)((s3 >> jj) & 1u), a3);
        }
      }
      float accs[4] = {a0, a1, a2, a3};

      const float inv = G[ocl] / sqrtf(Vr[ocl] + EPSf);
      const float mean = Mn[ocl], beta = Be[ocl];
      float v = 0.f;
#pragma unroll
      for (int t = 0; t < TT; ++t) {
        float xm = accs[t] - mean;
        float y = xm * inv;
        y = y + beta;
        float d = (y - v) * 0.5f;
        v = v + d;
        const bool sp = (v >= 1.0f);
        const size_t widx = ((size_t)(t * BB + b) * 768 + oc) * 8 + (n >> 5);
        const uint bit = 1u << (n & 31);
        if (sp) atomicOr(&qp32[widx], bit);
        else atomicAnd(&qp32[widx], ~bit);
        if (sp) v = 0.f;
      }
    }
  }
}

// ---------------------------------------------------------------------------
// K6: MFMA attention. [validated R16]
// ---------------------------------------------------------------------------
__global__ __launch_bounds__(1024) void k_attn(const ushort* __restrict__ qp,
                                               uchar* __restrict__ attnF) {
  __shared__ uint Qb[32][8], Kb[32][8], Vb[32][8];
  __shared__ ushort KtVT[32][40];
  const int tid = threadIdx.x;
  const int b = blockIdx.x >> 3;
  const int h = blockIdx.x & 7;
  const int lane = tid & 63;
  const int nt = tid >> 6;
  const int l15 = lane & 15, lhi = lane >> 4;
  const int n = nt * 16 + l15;
  const int wq = n >> 5, bitn = n & 31;

  float vst[8];
#pragma unroll
  for (int j = 0; j < 8; ++j) vst[j] = 0.f;

  for (int t = 0; t < TT; ++t) {
    __syncthreads();
    const ushort* base = qp + (size_t)(t * BB + b) * 768 * 16;
    if (tid < 768) {
      const int arr = tid >> 8;
      const int idx = tid & 255;
      const int ch = idx >> 3, wv2 = idx & 7;
      const uint val = *reinterpret_cast<const uint*>(
          base + (size_t)(arr * 256 + h * 32 + ch) * 16 + wv2 * 2);
      uint(*dst)[8] = (arr == 0) ? Qb : (arr == 1) ? Kb : Vb;
      dst[ch][wv2] = val;
    }
    __syncthreads();
    {
      const int ii = tid >> 5, jj = tid & 31;
      int s = 0;
#pragma unroll
      for (int w8 = 0; w8 < 8; ++w8) s += __popc(Kb[ii][w8] & Vb[jj][w8]);
      KtVT[jj][ii] = f2bf_rn((float)s);
    }
    __syncthreads();

    s16x8 bq;
#pragma unroll
    for (int k = 0; k < 8; ++k) {
      const uint qwv = Qb[lhi * 8 + k][wq];
      bq[k] = (short)(((qwv >> bitn) & 1u) ? 0x3F80 : 0);
    }
    s16x8 a0 = *reinterpret_cast<const s16x8*>(&KtVT[l15][lhi * 8]);
    s16x8 a1 = *reinterpret_cast<const s16x8*>(&KtVT[16 + l15][lhi * 8]);
    f32x4 acc0 = (f32x4){0.f, 0.f, 0.f, 0.f};
    f32x4 acc1 = (f32x4){0.f, 0.f, 0.f, 0.f};
    acc0 = __builtin_amdgcn_mfma_f32_16x16x32_bf16(a0, bq, acc0, 0, 0, 0);
    acc1 = __builtin_amdgcn_mfma_f32_16x16x32_bf16(a1, bq, acc1, 0, 0, 0);

    ushort sb[8];
    {
#pragma clang fp contract(off)
#pragma unroll
      for (int mt = 0; mt < 2; ++mt)
#pragma unroll
        for (int r = 0; r < 4; ++r) {
          const float av = (mt == 0) ? acc0[r] : acc1[r];
          float y = av * MULTf;
          float v = vst[mt * 4 + r];
          float d = (y - v) * 0.5f;
          v = v + d;
          const bool sp = (v >= 1.0f);
          sb[mt * 4 + r] = sp ? (ushort)0x3F80 : (ushort)0;
          vst[mt * 4 + r] = sp ? 0.f : v;
        }
    }
#pragma unroll
    for (int mt = 0; mt < 2; ++mt) {
      uint2 o;
      o.x = (uint)sb[mt * 4 + 0] | ((uint)sb[mt * 4 + 1] << 16);
      o.y = (uint)sb[mt * 4 + 2] | ((uint)sb[mt * 4 + 3] << 16);
      const int oct2 = mt * 2 + (lhi >> 1);
      uchar* dst = attnF +
                   ((((size_t)(t * BB + b) * 16 + nt) * 512 + h * 64 + oct2 * 16 + l15) * 16) +
                   (lhi & 1) * 8;
      *reinterpret_cast<uint2*>(dst) = o;
    }
  }
}

// ---------------------------------------------------------------------------
// K7: proj conv (MFMA, 2-split) + BN -> f32 out. ks-OUTER loads. [R14/R15/R16]
// ---------------------------------------------------------------------------
__global__ __launch_bounds__(256, 4) void k_proj_mfma(
    const uchar* __restrict__ attnF, const uchar* __restrict__ wfp,
    const float* __restrict__ pga, const float* __restrict__ pbe,
    const float* __restrict__ pme, const float* __restrict__ pva,
    float* __restrict__ out) {
  const int tid = threadIdx.x;
  const int w = tid >> 6, lane = tid & 63;
  const int lhi = lane >> 4, llo = lane & 15;
  const int wr = w >> 1, wc = w & 1;
  const int bid = blockIdx.x;
  const int xcd = bid & 7;
  const int r = bid >> 3;
  const int j = r & 3;
  const int g = (r >> 2) * 8 + xcd;
  const int tb = g >> 2, ntile = g & 3;
  const int oc0 = j * 64;
  const int nb0 = ntile * 4 + wc * 2;

  f32x4 acc[2][2];
#pragma unroll
  for (int mf = 0; mf < 2; ++mf)
#pragma unroll
    for (int nf = 0; nf < 2; ++nf) acc[mf][nf] = (f32x4){0.f, 0.f, 0.f, 0.f};

#pragma unroll
  for (int ks = 0; ks < 8; ++ks) {
    s16x8 wf[2][2];
#pragma unroll
    for (int s = 0; s < 2; ++s)
#pragma unroll
      for (int mf = 0; mf < 2; ++mf) {
        const int ob = j * 4 + wr * 2 + mf;
        wf[s][mf] = *reinterpret_cast<const s16x8*>(
            wfp + ((((size_t)s * 16 + ob) * 8 + ks) * 64 + lane) * 16);
      }
    s16x8 bf0 = *reinterpret_cast<const s16x8*>(
        attnF + ((((size_t)tb * 16 + nb0) * 512 + ks * 64 + lane) * 16));
    s16x8 bf1 = *reinterpret_cast<const s16x8*>(
        attnF + ((((size_t)tb * 16 + nb0 + 1) * 512 + ks * 64 + lane) * 16));
#pragma unroll
    for (int s = 0; s < 2; ++s)
#pragma unroll
      for (int mf = 0; mf < 2; ++mf) {
        acc[mf][0] = __builtin_amdgcn_mfma_f32_16x16x32_bf16(wf[s][mf], bf0, acc[mf][0], 0, 0, 0);
        acc[mf][1] = __builtin_amdgcn_mfma_f32_16x16x32_bf16(wf[s][mf], bf1, acc[mf][1], 0, 0, 0);
      }
  }

  float inv8[2][4], mean8[2][4], beta8[2][4];
#pragma unroll
  for (int mf = 0; mf < 2; ++mf)
#pragma unroll
    for (int rr = 0; rr < 4; ++rr) {
      const int ocb = oc0 + wr * 32 + mf * 16 + lhi * 4 + rr;
      inv8[mf][rr] = pga[ocb] / sqrtf(pva[ocb] + EPSf);
      mean8[mf][rr] = pme[ocb];
      beta8[mf][rr] = pbe[ocb];
    }

#pragma unroll
  for (int mf = 0; mf < 2; ++mf)
#pragma unroll
    for (int nf = 0; nf < 2; ++nf)
#pragma unroll
      for (int rr = 0; rr < 4; ++rr) {
        const int oc = oc0 + wr * 32 + mf * 16 + lhi * 4 + rr;
        const int nn = ntile * 64 + wc * 32 + nf * 16 + llo;
        float y = (acc[mf][nf][rr] - mean8[mf][rr]) * inv8[mf][rr] + beta8[mf][rr];
        out[((size_t)tb * CC + oc) * NN + nn] = y;
      }
}

// ---------------------------------------------------------------------------
extern "C" void kernel_launch(void* const* d_in, const int* in_sizes, int n_in,
                              void* d_out, int out_size, void* d_ws, size_t ws_size,
                              hipStream_t stream) {
  const float* x = (const float*)d_in[0];
  const float* q_w = (const float*)d_in[1];
  const float* q_g = (const float*)d_in[2];
  const float* q_b = (const float*)d_in[3];
  const float* q_m = (const float*)d_in[4];
  const float* q_v = (const float*)d_in[5];
  const float* k_w = (const float*)d_in[6];
  const float* k_g = (const float*)d_in[7];
  const float* k_b = (const float*)d_in[8];
  const float* k_m = (const float*)d_in[9];
  const float* k_v = (const float*)d_in[10];
  const float* v_w = (const float*)d_in[11];
  const float* v_g = (const float*)d_in[12];
  const float* v_b = (const float*)d_in[13];
  const float* v_m = (const float*)d_in[14];
  const float* v_v = (const float*)d_in[15];
  const float* p_w = (const float*)d_in[16];
  const float* p_g = (const float*)d_in[17];
  const float* p_b = (const float*)d_in[18];
  const float* p_m = (const float*)d_in[19];
  const float* p_v = (const float*)d_in[20];

  uchar* ws = (uchar*)d_ws;
  uchar* xsF  = ws;                         // 16 MiB frags (reused as attnF)
  ushort* qp  = (ushort*)(ws + 16777216);   // 3 MiB packed q/k/v spikes
  uchar* wfq  = ws + 19922944;              // 384 KiB single-split scaled
  uchar* wfp  = ws + 20447232;              // 256 KiB proj 2-split
  uchar* xsP  = ws + 20971520;              // 1 MiB bit-packed xs spikes

  k_front<<<dim3(384), 256, 0, stream>>>(x, xsF, xsP, q_w, k_w, v_w, p_w,
                                         q_g, q_v, k_g, k_v, v_g, v_v,
                                         wfq, wfp);
  k_qkv_mfma<<<dim3(1536), 256, 0, stream>>>(xsF, wfq, xsP, q_w, k_w, v_w,
                                             q_g, q_b, q_m, q_v,
                                             k_g, k_b, k_m, k_v,
                                             v_g, v_b, v_m, v_v,
                                             qp);
  k_attn<<<dim3(256), 1024, 0, stream>>>(qp, xsF /* attnF shares region */);
  k_proj_mfma<<<dim3(2048), 256, 0, stream>>>(xsF, wfp, p_g, p_b, p_m, p_v,
                                              (float*)d_out);
}

// Round 18
// 96.520 us; speedup vs baseline: 1.2579x; 1.2579x over previous
//
#include <hip/hip_runtime.h>

#define TT 4
#define BB 32
#define CC 256
#define NN 256
#define EPSf 1e-5f
#define MULTf 0.35355339059327373f
#define MARGINQ 1e-2f
#define BCAP 8192u

typedef __attribute__((ext_vector_type(8))) short s16x8;
typedef __attribute__((ext_vector_type(4))) float f32x4;
typedef unsigned char uchar;
typedef unsigned int uint;
typedef unsigned short ushort;

__device__ __forceinline__ ushort f2bf_rn(float f) {
  uint u = __float_as_uint(f);
  u = (u + 0x7FFFu + ((u >> 16) & 1u)) >> 16;
  return (ushort)u;
}
__device__ __forceinline__ float bf2f(ushort b) {
  return __uint_as_float(((uint)b) << 16);
}

// ---------------------------------------------------------------------------
// K1 (front): blocks 0..255 = lif(x) -> xsF fragments + xsP packed bits;
// blocks 256..383 = weight prep (qkv single-split scaled; proj 2-split);
// zeroes the 256 flag-bucket counters.  [validated R16]
// ---------------------------------------------------------------------------
__global__ __launch_bounds__(256) void k_front(
    const float* __restrict__ x, uchar* __restrict__ xsF, uchar* __restrict__ xsP,
    const float* __restrict__ qw, const float* __restrict__ kw,
    const float* __restrict__ vw, const float* __restrict__ pw,
    const float* __restrict__ qga, const float* __restrict__ qva,
    const float* __restrict__ kga, const float* __restrict__ kva,
    const float* __restrict__ vga, const float* __restrict__ vva,
    uchar* __restrict__ wfq, uchar* __restrict__ wfp, uint* __restrict__ flags) {
  const int tid = threadIdx.x;
  const int bid = blockIdx.x;
  if (bid < 256) {
#pragma clang fp contract(off)
    const int b = bid >> 3;
    const int ksq = bid & 7;
    const int oct = tid >> 6;    // 0..3
    const int nq = tid & 63;     // n-quad
    const int c0 = ksq * 32 + oct * 8;
    const int n0 = nq * 4;
    const size_t stride = (size_t)BB * CC * NN;
    const float* xb = x + ((size_t)b * CC + c0) * NN + n0;

    float v[8][4];
#pragma unroll
    for (int j = 0; j < 8; ++j)
#pragma unroll
      for (int nn = 0; nn < 4; ++nn) v[j][nn] = 0.f;

#pragma unroll
    for (int t = 0; t < TT; ++t) {
      ushort sp[8][4];
      uint pm[4] = {0, 0, 0, 0};
#pragma unroll
      for (int j = 0; j < 8; ++j) {
        const float4 xv = *reinterpret_cast<const float4*>(xb + t * stride + (size_t)j * NN);
        const float xa[4] = {xv.x, xv.y, xv.z, xv.w};
#pragma unroll
        for (int nn = 0; nn < 4; ++nn) {
          float d = (xa[nn] - v[j][nn]) * 0.5f;
          v[j][nn] = v[j][nn] + d;
          bool s = (v[j][nn] >= 1.0f);
          sp[j][nn] = s ? (ushort)0x3F80 : (ushort)0;
          if (s) { v[j][nn] = 0.f; pm[nn] |= 1u << j; }
        }
      }
#pragma unroll
      for (int nn = 0; nn < 4; ++nn) {
        const int n = n0 + nn;
        uint4* dst = reinterpret_cast<uint4*>(xsF) +
                     (((size_t)(t * BB + b) * 16 + (n >> 4)) * 512 + ksq * 64 + oct * 16 + (n & 15));
        uint4 o;
        o.x = (uint)sp[0][nn] | ((uint)sp[1][nn] << 16);
        o.y = (uint)sp[2][nn] | ((uint)sp[3][nn] << 16);
        o.z = (uint)sp[4][nn] | ((uint)sp[5][nn] << 16);
        o.w = (uint)sp[6][nn] | ((uint)sp[7][nn] << 16);
        *dst = o;
        xsP[(((size_t)(t * BB + b) * NN + n) << 5) + ksq * 4 + oct] = (uchar)pm[nn];
      }
    }
  } else {
    const int gid = (bid - 256) * 256 + tid;  // 0..32767
    if (gid < 256) flags[gid] = 0;            // bucket counters
    const int ob2 = gid >> 9;                 // 0..63
    const int e = gid & 511;
    const int ks = e >> 6, l = e & 63;
    const int c0 = ks * 32 + (l >> 4) * 8;
    if (ob2 < 48) {
      const int sel = ob2 >> 4;
      const float* Wb = sel == 0 ? qw : (sel == 1 ? kw : vw);
      const float* G = sel == 0 ? qga : (sel == 1 ? kga : vga);
      const float* Vr = sel == 0 ? qva : (sel == 1 ? kva : vva);
      const int ocr = (ob2 & 15) * 16 + (l & 15);
      const float inv = G[ocr] / sqrtf(Vr[ocr] + EPSf);
      const float* W = Wb + (size_t)ocr * CC;
      float wv[8];
      *reinterpret_cast<float4*>(&wv[0]) = *reinterpret_cast<const float4*>(W + c0);
      *reinterpret_cast<float4*>(&wv[4]) = *reinterpret_cast<const float4*>(W + c0 + 4);
      ushort hi[8];
#pragma unroll
      for (int j = 0; j < 8; ++j) hi[j] = f2bf_rn(wv[j] * inv);
      *reinterpret_cast<uint4*>(wfq + (((size_t)ob2 * 8 + ks) * 64 + l) * 16) =
          *reinterpret_cast<const uint4*>(hi);
    } else {
      const int ob = ob2 - 48;
      const float* W = pw + ((size_t)(ob * 16 + (l & 15))) * CC;
      float wv[8];
      *reinterpret_cast<float4*>(&wv[0]) = *reinterpret_cast<const float4*>(W + c0);
      *reinterpret_cast<float4*>(&wv[4]) = *reinterpret_cast<const float4*>(W + c0 + 4);
      ushort hi[8], lo[8];
#pragma unroll
      for (int j = 0; j < 8; ++j) {
        hi[j] = f2bf_rn(wv[j]);
        lo[j] = f2bf_rn(wv[j] - bf2f(hi[j]));
      }
      const size_t base = (((size_t)ob * 8 + ks) * 64 + l) * 16;
      const size_t sstr = (size_t)16 * 8 * 64 * 16;
      *reinterpret_cast<uint4*>(wfp + base) = *reinterpret_cast<const uint4*>(hi);
      *reinterpret_cast<uint4*>(wfp + sstr + base) = *reinterpret_cast<const uint4*>(lo);
    }
  }
}

// ---------------------------------------------------------------------------
// K4: fused q/k/v conv (MFMA, single-split scaled bf16) + folded-BN + LIF.
// Flags go to per-(b,h) buckets.  [validated R16]
// ---------------------------------------------------------------------------
__global__ __launch_bounds__(256, 2) void k_qkv_mfma(
    const uchar* __restrict__ xsF, const uchar* __restrict__ wfq,
    const float* __restrict__ qga, const float* __restrict__ qbe, const float* __restrict__ qme, const float* __restrict__ qva,
    const float* __restrict__ kga, const float* __restrict__ kbe, const float* __restrict__ kme, const float* __restrict__ kva,
    const float* __restrict__ vga, const float* __restrict__ vbe, const float* __restrict__ vme, const float* __restrict__ vva,
    ushort* __restrict__ qp, uint* __restrict__ flags) {
  const int tid = threadIdx.x;
  const int wc = tid >> 6, lane = tid & 63;
  const int lhi = lane >> 4, llo = lane & 15;
  const int bid = blockIdx.x;
  const int xcd = bid & 7;
  const int r0 = bid >> 3;
  const int j = r0 % 12;                // oc-block 0..11
  const int g = (r0 / 12) * 8 + xcd;    // group 0..127
  const int b = g >> 2, ntile = g & 3;
  const int oc0 = j * 64;
  const int sel = j >> 2;
  const float* G  = sel == 0 ? qga : (sel == 1 ? kga : vga);
  const float* Be = sel == 0 ? qbe : (sel == 1 ? kbe : vbe);
  const float* Mn = sel == 0 ? qme : (sel == 1 ? kme : vme);
  const float* Vr = sel == 0 ? qva : (sel == 1 ? kva : vva);

  s16x8 wfr[4][8];
#pragma unroll
  for (int mf = 0; mf < 4; ++mf)
#pragma unroll
    for (int ks = 0; ks < 8; ++ks)
      wfr[mf][ks] = *reinterpret_cast<const s16x8*>(
          wfq + (((size_t)(j * 4 + mf) * 8 + ks) * 64 + lane) * 16);

  float bias8[4][4];
#pragma unroll
  for (int mf = 0; mf < 4; ++mf)
#pragma unroll
    for (int rr = 0; rr < 4; ++rr) {
      const int ocb = (j & 3) * 64 + mf * 16 + lhi * 4 + rr;
      const float inv = G[ocb] / sqrtf(Vr[ocb] + EPSf);
      bias8[mf][rr] = Be[ocb] - Mn[ocb] * inv;
    }

  float vst[4][4];
#pragma unroll
  for (int mf = 0; mf < 4; ++mf)
#pragma unroll
    for (int rr = 0; rr < 4; ++rr) vst[mf][rr] = 0.f;
  uint fl = 0;
  ushort qm[TT][4];
  const int nb = ntile * 4 + wc;

#define BPTR(t_, ks_)                                                   \
  reinterpret_cast<const s16x8*>(                                       \
      xsF + ((((size_t)((t_) * BB + b) * 16 + nb) * 512 + (ks_) * 64 + lane) * 16))

  s16x8 bfr[8];
#pragma unroll
  for (int ks = 0; ks < 8; ++ks) bfr[ks] = *BPTR(0, ks);

#pragma unroll
  for (int t = 0; t < TT; ++t) {
    f32x4 acc[4];
#pragma unroll
    for (int mf = 0; mf < 4; ++mf) acc[mf] = (f32x4){0.f, 0.f, 0.f, 0.f};

#pragma unroll
    for (int ks = 0; ks < 8; ++ks) {
#pragma unroll
      for (int mf = 0; mf < 4; ++mf)
        acc[mf] = __builtin_amdgcn_mfma_f32_16x16x32_bf16(wfr[mf][ks], bfr[ks], acc[mf], 0, 0, 0);
      if (t < TT - 1) bfr[ks] = *BPTR(t + 1, ks);
    }

#pragma unroll
    for (int mf = 0; mf < 4; ++mf)
#pragma unroll
      for (int rr = 0; rr < 4; ++rr) {
        float y = acc[mf][rr] + bias8[mf][rr];
        float v = vst[mf][rr];
        v = v + (y - v) * 0.5f;
        const bool sp = (v >= 1.0f);
        if (fabsf(v - 1.0f) < MARGINQ) fl |= 1u << (mf * 4 + rr);
        const unsigned long long m = __ballot(sp);
        if (llo == rr) qm[t][mf] = (ushort)((m >> (lhi * 16)) & 0xFFFFull);
        vst[mf][rr] = sp ? 0.f : v;
      }
  }
#undef BPTR

  if (llo < 4) {
#pragma unroll
    for (int t = 0; t < TT; ++t) {
      ushort* qrow = qp + (size_t)(t * BB + b) * 768 * 16;
#pragma unroll
      for (int mf = 0; mf < 4; ++mf) {
        const int oc = oc0 + mf * 16 + lhi * 4 + llo;
        qrow[(size_t)oc * 16 + ntile * 4 + wc] = qm[t][mf];
      }
    }
  }

  if (fl) {
#pragma unroll
    for (int mf = 0; mf < 4; ++mf)
#pragma unroll
      for (int rr = 0; rr < 4; ++rr)
        if (fl & (1u << (mf * 4 + rr))) {
          const int oc = oc0 + mf * 16 + lhi * 4 + rr;
          const int n = ntile * 64 + wc * 16 + llo;
          const uint bucket = ((uint)b << 3) | (uint)((oc & 255) >> 5);
          const uint idx = atomicAdd(&flags[bucket], 1u);
          if (idx < BCAP)
            flags[256 + (bucket << 13) + idx] =
                (((uint)(b << 10) | (uint)oc) << 8) | (uint)n;
        }
  }
}

// ---------------------------------------------------------------------------
// K5: standalone bucketed exact fixer. [validated R13/R15/R16]
// ---------------------------------------------------------------------------
__global__ __launch_bounds__(256) void k_fix(
    const uchar* __restrict__ xsP,
    const float* __restrict__ qw, const float* __restrict__ kw, const float* __restrict__ vw,
    const float* __restrict__ qga, const float* __restrict__ qbe, const float* __restrict__ qme, const float* __restrict__ qva,
    const float* __restrict__ kga, const float* __restrict__ kbe, const float* __restrict__ kme, const float* __restrict__ kva,
    const float* __restrict__ vga, const float* __restrict__ vbe, const float* __restrict__ vme, const float* __restrict__ vva,
    uint* __restrict__ qp32, const uint* __restrict__ flags) {
#pragma clang fp contract(off)
  const uint bucket = blockIdx.x;
  const int b = (int)(bucket >> 3);
  const uint cnt = min(flags[bucket], BCAP);
  for (uint i = threadIdx.x; i < cnt; i += 256) {
    const uint e = flags[256 + (bucket << 13) + i];
    const int n = (int)(e & 255);
    const int oc = (int)((e >> 8) & 1023);
    const int sel = oc >> 8, ocl = oc & 255;
    const float* W = (sel == 0 ? qw : (sel == 1 ? kw : vw)) + (size_t)ocl * CC;
    const float* G  = sel == 0 ? qga : (sel == 1 ? kga : vga);
    const float* Be = sel == 0 ? qbe : (sel == 1 ? kbe : vbe);
    const float* Mn = sel == 0 ? qme : (sel == 1 ? kme : vme);
    const float* Vr = sel == 0 ? qva : (sel == 1 ? kva : vva);

    uint bw[4][8];
#pragma unroll
    for (int t = 0; t < TT; ++t) {
      const uint4* p = reinterpret_cast<const uint4*>(
          xsP + (((size_t)(t * BB + b) * NN + n) << 5));
      uint4 a = p[0], c4 = p[1];
      bw[t][0] = a.x;  bw[t][1] = a.y;  bw[t][2] = a.z;  bw[t][3] = a.w;
      bw[t][4] = c4.x; bw[t][5] = c4.y; bw[t][6] = c4.z; bw[t][7] = c4.w;
    }

    const float4* W4 = reinterpret_cast<const float4*>(W);
    float a0 = 0.f, a1 = 0.f, a2 = 0.f, a3 = 0.f;
#pragma unroll
    for (int gg = 0; gg < 32; ++gg) {
      const float4 w0 = W4[2 * gg];
      const float4 w1 = W4[2 * gg + 1];
      const uint s0 = bw[0][gg >> 2] >> ((gg & 3) * 8);
      const uint s1 = bw[1][gg >> 2] >> ((gg & 3) * 8);
      const uint s2 = bw[2][gg >> 2] >> ((gg & 3) * 8);
      const uint s3 = bw[3][gg >> 2] >> ((gg & 3) * 8);
      const float wv[8] = {w0.x, w0.y, w0.z, w0.w, w1.x, w1.y, w1.z, w1.w};
#pragma unroll
      for (int jj = 0; jj < 8; ++jj) {
        a0 = fmaf(wv[jj], (float)((s0 >> jj) & 1u), a0);
        a1 = fmaf(wv[jj], (float)((s1 >> jj) & 1u), a1);
        a2 = fmaf(wv[jj], (float)((s2 >> jj) & 1u), a2);
        a3 = fmaf(wv[jj], (float)((s3 >> jj) & 1u), a3);
      }
    }
    float accs[4] = {a0, a1, a2, a3};

    const float inv = G[ocl] / sqrtf(Vr[ocl] + EPSf);
    const float mean = Mn[ocl], beta = Be[ocl];
    float v = 0.f;
#pragma unroll
    for (int t = 0; t < TT; ++t) {
      float xm = accs[t] - mean;
      float y = xm * inv;
      y = y + beta;
      float d = (y - v) * 0.5f;
      v = v + d;
      const bool sp = (v >= 1.0f);
      const size_t widx = ((size_t)(t * BB + b) * 768 + oc) * 8 + (n >> 5);
      const uint bit = 1u << (n & 31);
      if (sp) atomicOr(&qp32[widx], bit);
      else atomicAnd(&qp32[widx], ~bit);
      if (sp) v = 0.f;
    }
  }
}

// ---------------------------------------------------------------------------
// K6: MFMA attention. Q(KtV)*2scale + LIF, exact integers end-to-end.
// [validated R16]
// ---------------------------------------------------------------------------
__global__ __launch_bounds__(1024) void k_attn(const ushort* __restrict__ qp,
                                               uchar* __restrict__ attnF) {
  __shared__ uint Qb[32][8], Kb[32][8], Vb[32][8];
  __shared__ ushort KtVT[32][40];
  const int tid = threadIdx.x;
  const int b = blockIdx.x >> 3;
  const int h = blockIdx.x & 7;
  const int lane = tid & 63;
  const int nt = tid >> 6;
  const int l15 = lane & 15, lhi = lane >> 4;
  const int n = nt * 16 + l15;
  const int wq = n >> 5, bitn = n & 31;

  float vst[8];
#pragma unroll
  for (int j = 0; j < 8; ++j) vst[j] = 0.f;

  for (int t = 0; t < TT; ++t) {
    __syncthreads();
    const ushort* base = qp + (size_t)(t * BB + b) * 768 * 16;
    if (tid < 768) {
      const int arr = tid >> 8;
      const int idx = tid & 255;
      const int ch = idx >> 3, wv2 = idx & 7;
      const uint val = *reinterpret_cast<const uint*>(
          base + (size_t)(arr * 256 + h * 32 + ch) * 16 + wv2 * 2);
      uint(*dst)[8] = (arr == 0) ? Qb : (arr == 1) ? Kb : Vb;
      dst[ch][wv2] = val;
    }
    __syncthreads();
    {
      const int ii = tid >> 5, jj = tid & 31;
      int s = 0;
#pragma unroll
      for (int w8 = 0; w8 < 8; ++w8) s += __popc(Kb[ii][w8] & Vb[jj][w8]);
      KtVT[jj][ii] = f2bf_rn((float)s);
    }
    __syncthreads();

    s16x8 bq;
#pragma unroll
    for (int k = 0; k < 8; ++k) {
      const uint qwv = Qb[lhi * 8 + k][wq];
      bq[k] = (short)(((qwv >> bitn) & 1u) ? 0x3F80 : 0);
    }
    s16x8 a0 = *reinterpret_cast<const s16x8*>(&KtVT[l15][lhi * 8]);
    s16x8 a1 = *reinterpret_cast<const s16x8*>(&KtVT[16 + l15][lhi * 8]);
    f32x4 acc0 = (f32x4){0.f, 0.f, 0.f, 0.f};
    f32x4 acc1 = (f32x4){0.f, 0.f, 0.f, 0.f};
    acc0 = __builtin_amdgcn_mfma_f32_16x16x32_bf16(a0, bq, acc0, 0, 0, 0);
    acc1 = __builtin_amdgcn_mfma_f32_16x16x32_bf16(a1, bq, acc1, 0, 0, 0);

    ushort sb[8];
    {
#pragma clang fp contract(off)
#pragma unroll
      for (int mt = 0; mt < 2; ++mt)
#pragma unroll
        for (int r = 0; r < 4; ++r) {
          const float av = (mt == 0) ? acc0[r] : acc1[r];
          float y = av * MULTf;
          float v = vst[mt * 4 + r];
          float d = (y - v) * 0.5f;
          v = v + d;
          const bool sp = (v >= 1.0f);
          sb[mt * 4 + r] = sp ? (ushort)0x3F80 : (ushort)0;
          vst[mt * 4 + r] = sp ? 0.f : v;
        }
    }
#pragma unroll
    for (int mt = 0; mt < 2; ++mt) {
      uint2 o;
      o.x = (uint)sb[mt * 4 + 0] | ((uint)sb[mt * 4 + 1] << 16);
      o.y = (uint)sb[mt * 4 + 2] | ((uint)sb[mt * 4 + 3] << 16);
      const int oct2 = mt * 2 + (lhi >> 1);
      uchar* dst = attnF +
                   ((((size_t)(t * BB + b) * 16 + nt) * 512 + h * 64 + oct2 * 16 + l15) * 16) +
                   (lhi & 1) * 8;
      *reinterpret_cast<uint2*>(dst) = o;
    }
  }
}

// ---------------------------------------------------------------------------
// K7: proj conv (MFMA, 2-split) + BN -> f32 out. ks-OUTER loads. [R16]
// ---------------------------------------------------------------------------
__global__ __launch_bounds__(256, 4) void k_proj_mfma(
    const uchar* __restrict__ attnF, const uchar* __restrict__ wfp,
    const float* __restrict__ pga, const float* __restrict__ pbe,
    const float* __restrict__ pme, const float* __restrict__ pva,
    float* __restrict__ out) {
  const int tid = threadIdx.x;
  const int w = tid >> 6, lane = tid & 63;
  const int lhi = lane >> 4, llo = lane & 15;
  const int wr = w >> 1, wc = w & 1;
  const int bid = blockIdx.x;
  const int xcd = bid & 7;
  const int r = bid >> 3;
  const int j = r & 3;
  const int g = (r >> 2) * 8 + xcd;
  const int tb = g >> 2, ntile = g & 3;
  const int oc0 = j * 64;
  const int nb0 = ntile * 4 + wc * 2;

  f32x4 acc[2][2];
#pragma unroll
  for (int mf = 0; mf < 2; ++mf)
#pragma unroll
    for (int nf = 0; nf < 2; ++nf) acc[mf][nf] = (f32x4){0.f, 0.f, 0.f, 0.f};

#pragma unroll
  for (int ks = 0; ks < 8; ++ks) {
    s16x8 wf[2][2];
#pragma unroll
    for (int s = 0; s < 2; ++s)
#pragma unroll
      for (int mf = 0; mf < 2; ++mf) {
        const int ob = j * 4 + wr * 2 + mf;
        wf[s][mf] = *reinterpret_cast<const s16x8*>(
            wfp + ((((size_t)s * 16 + ob) * 8 + ks) * 64 + lane) * 16);
      }
    s16x8 bf0 = *reinterpret_cast<const s16x8*>(
        attnF + ((((size_t)tb * 16 + nb0) * 512 + ks * 64 + lane) * 16));
    s16x8 bf1 = *reinterpret_cast<const s16x8*>(
        attnF + ((((size_t)tb * 16 + nb0 + 1) * 512 + ks * 64 + lane) * 16));
#pragma unroll
    for (int s = 0; s < 2; ++s)
#pragma unroll
      for (int mf = 0; mf < 2; ++mf) {
        acc[mf][0] = __builtin_amdgcn_mfma_f32_16x16x32_bf16(wf[s][mf], bf0, acc[mf][0], 0, 0, 0);
        acc[mf][1] = __builtin_amdgcn_mfma_f32_16x16x32_bf16(wf[s][mf], bf1, acc[mf][1], 0, 0, 0);
      }
  }

  float inv8[2][4], mean8[2][4], beta8[2][4];
#pragma unroll
  for (int mf = 0; mf < 2; ++mf)
#pragma unroll
    for (int rr = 0; rr < 4; ++rr) {
      const int ocb = oc0 + wr * 32 + mf * 16 + lhi * 4 + rr;
      inv8[mf][rr] = pga[ocb] / sqrtf(pva[ocb] + EPSf);
      mean8[mf][rr] = pme[ocb];
      beta8[mf][rr] = pbe[ocb];
    }

#pragma unroll
  for (int mf = 0; mf < 2; ++mf)
#pragma unroll
    for (int nf = 0; nf < 2; ++nf)
#pragma unroll
      for (int rr = 0; rr < 4; ++rr) {
        const int oc = oc0 + wr * 32 + mf * 16 + lhi * 4 + rr;
        const int nn = ntile * 64 + wc * 32 + nf * 16 + llo;
        float y = (acc[mf][nf][rr] - mean8[mf][rr]) * inv8[mf][rr] + beta8[mf][rr];
        out[((size_t)tb * CC + oc) * NN + nn] = y;
      }
}

// ---------------------------------------------------------------------------
extern "C" void kernel_launch(void* const* d_in, const int* in_sizes, int n_in,
                              void* d_out, int out_size, void* d_ws, size_t ws_size,
                              hipStream_t stream) {
  const float* x = (const float*)d_in[0];
  const float* q_w = (const float*)d_in[1];
  const float* q_g = (const float*)d_in[2];
  const float* q_b = (const float*)d_in[3];
  const float* q_m = (const float*)d_in[4];
  const float* q_v = (const float*)d_in[5];
  const float* k_w = (const float*)d_in[6];
  const float* k_g = (const float*)d_in[7];
  const float* k_b = (const float*)d_in[8];
  const float* k_m = (const float*)d_in[9];
  const float* k_v = (const float*)d_in[10];
  const float* v_w = (const float*)d_in[11];
  const float* v_g = (const float*)d_in[12];
  const float* v_b = (const float*)d_in[13];
  const float* v_m = (const float*)d_in[14];
  const float* v_v = (const float*)d_in[15];
  const float* p_w = (const float*)d_in[16];
  const float* p_g = (const float*)d_in[17];
  const float* p_b = (const float*)d_in[18];
  const float* p_m = (const float*)d_in[19];
  const float* p_v = (const float*)d_in[20];

  uchar* ws = (uchar*)d_ws;
  uchar* xsF  = ws;                         // 16 MiB frags (reused as attnF)
  ushort* qp  = (ushort*)(ws + 16777216);   // 3 MiB packed q/k/v spikes
  uchar* wfq  = ws + 19922944;              // 384 KiB single-split scaled
  uchar* wfp  = ws + 20447232;              // 256 KiB proj 2-split
  uchar* xsP  = ws + 20971520;              // 1 MiB bit-packed xs spikes
  uint* flags = (uint*)(ws + 22020096);     // 256 counters + 256*8192 entries

  k_front<<<dim3(384), 256, 0, stream>>>(x, xsF, xsP, q_w, k_w, v_w, p_w,
                                         q_g, q_v, k_g, k_v, v_g, v_v,
                                         wfq, wfp, flags);
  k_qkv_mfma<<<dim3(1536), 256, 0, stream>>>(xsF, wfq,
                                             q_g, q_b, q_m, q_v,
                                             k_g, k_b, k_m, k_v,
                                             v_g, v_b, v_m, v_v,
                                             qp, flags);
  k_fix<<<dim3(256), 256, 0, stream>>>(xsP, q_w, k_w, v_w,
                                       q_g, q_b, q_m, q_v,
                                       k_g, k_b, k_m, k_v,
                                       v_g, v_b, v_m, v_v,
                                       (uint*)qp, flags);
  k_attn<<<dim3(256), 1024, 0, stream>>>(qp, xsF /* attnF shares region */);
  k_proj_mfma<<<dim3(2048), 256, 0, stream>>>(xsF, wfp, p_g, p_b, p_m, p_v,
                                              (float*)d_out);
}